// Round 3
// baseline (801.759 us; speedup 1.0000x reference)
//
#include <hip/hip_runtime.h>

// GCN layer on MI355X (gfx950) — ALL tensors fp32.
// x[100000,512], edge_index[2,3200000] i32, W1[512,16], b1[16], W2[16,2], b2[2]
//   -> out[100000,2] fp32.
//
// Math: s[j] = dinv[j] * (x@W1)[j],  dinv = rsqrt(indeg+1)
//   out_i = ( dinv[i] * ( sum_{edges j->i} s[j] + s[i] ) + b1 ) @ W2 + b2
//
// R3 structure: CSR build (deg -> scan -> fill) + fused gather/epilogue.
// No f32 atomics anywhere (R2 showed 51.2M write-through atomics = 200 MB
// WRITE_SIZE, 166 us).

constexpr int N_NODES = 100000;
constexpr int N_EDGES = 3200000;
constexpr int IN_CH   = 512;
constexpr int HID     = 16;
constexpr int NBLK    = (N_NODES + 255) / 256;  // 391 scan blocks

typedef __attribute__((ext_vector_type(8))) short short8;
typedef __attribute__((ext_vector_type(4))) float floatx4;

__device__ __forceinline__ short bf16_rne(float f) {
    unsigned u = __float_as_uint(f);
    unsigned r = 0x7fffu + ((u >> 16) & 1u);
    return (short)((u + r) >> 16);
}
__device__ __forceinline__ float bf16_to_f32(short s) {
    return __uint_as_float(((unsigned)(unsigned short)s) << 16);
}

// ---- workspace layout (bytes) ----
// [0       ,   400000) deg  : int[N_NODES]    (memset 0)
// [400000  ,   800000) offs : int[N_NODES]    exclusive scan of deg
// [800000  ,  1200000) curs : int[N_NODES]    fill cursors (copy of offs)
// [1200000 ,  1204096) bsum : int[1024]       block sums for scan
// [1204096 ,  1604096) dinv : float[N_NODES]
// [1604096 ,  8004096) xws  : float[N_NODES*16]
// [8004096 , 20804096) csr  : int[N_EDGES]    source node per CSR slot

__global__ __launch_bounds__(256) void deg_kernel(const int* __restrict__ col,
                                                  int* __restrict__ deg) {
    int i = blockIdx.x * 256 + threadIdx.x;
    if (i < N_EDGES) atomicAdd(&deg[col[i]], 1);
}

// Block-local exclusive scan; per-block totals to bsum.
__global__ __launch_bounds__(256) void scan1_kernel(const int* __restrict__ deg,
                                                    int* __restrict__ offs,
                                                    int* __restrict__ bsum) {
    __shared__ int tmp[256];
    int tid = threadIdx.x;
    int i = blockIdx.x * 256 + tid;
    int v = (i < N_NODES) ? deg[i] : 0;
    tmp[tid] = v;
    __syncthreads();
#pragma unroll
    for (int off = 1; off < 256; off <<= 1) {
        int t = (tid >= off) ? tmp[tid - off] : 0;
        __syncthreads();
        tmp[tid] += t;
        __syncthreads();
    }
    if (i < N_NODES) offs[i] = tmp[tid] - v;  // exclusive
    if (tid == 255) bsum[blockIdx.x] = tmp[255];
}

// Exclusive scan of the 391 block sums, one 512-thread block.
__global__ __launch_bounds__(512) void scan2_kernel(int* __restrict__ bsum) {
    __shared__ int tmp[512];
    int tid = threadIdx.x;
    int v = (tid < NBLK) ? bsum[tid] : 0;
    tmp[tid] = v;
    __syncthreads();
#pragma unroll
    for (int off = 1; off < 512; off <<= 1) {
        int t = (tid >= off) ? tmp[tid - off] : 0;
        __syncthreads();
        tmp[tid] += t;
        __syncthreads();
    }
    if (tid < NBLK) bsum[tid] = tmp[tid] - v;  // exclusive
}

// Add block base; also emit cursor copy and dinv.
__global__ __launch_bounds__(256) void scan3_kernel(const int* __restrict__ deg,
                                                    int* __restrict__ offs,
                                                    int* __restrict__ curs,
                                                    const int* __restrict__ bsum,
                                                    float* __restrict__ dinv) {
    int i = blockIdx.x * 256 + threadIdx.x;
    if (i >= N_NODES) return;
    int o = offs[i] + bsum[blockIdx.x];
    offs[i] = o;
    curs[i] = o;
    dinv[i] = rsqrtf((float)(deg[i] + 1));  // +1 self loop => > 0
}

__global__ __launch_bounds__(256) void fill_kernel(const int* __restrict__ ei,
                                                   int* __restrict__ curs,
                                                   int* __restrict__ csr) {
    int e = blockIdx.x * 256 + threadIdx.x;
    if (e >= N_EDGES) return;
    int c = ei[N_EDGES + e];              // target
    int pos = atomicAdd(&curs[c], 1);
    csr[pos] = ei[e];                     // source
}

// xws[n][h] = dinv[n] * sum_c x[n][c] * W1[c][h] via split-bf16 MFMA.
__global__ __launch_bounds__(256) void xw_kernel(const float* __restrict__ x,
                                                 const float* __restrict__ W1,
                                                 const float* __restrict__ dinv,
                                                 float* __restrict__ xws) {
    __shared__ short w1h[HID * IN_CH];
    __shared__ short w1l[HID * IN_CH];
    for (int idx = threadIdx.x; idx < IN_CH * HID; idx += 256) {
        int c = idx >> 4, h = idx & 15;
        float w = W1[idx];
        short hi = bf16_rne(w);
        short lo = bf16_rne(w - bf16_to_f32(hi));
        w1h[h * IN_CH + c] = hi;
        w1l[h * IN_CH + c] = lo;
    }
    __syncthreads();

    const int wave = threadIdx.x >> 6;
    const int lane = threadIdx.x & 63;
    const int quad = lane >> 4;
    const int m    = lane & 15;
    const int base = (blockIdx.x * 4 + wave) * 16;
    if (base >= N_NODES) return;

    int node_a = base + m;
    if (node_a >= N_NODES) node_a = N_NODES - 1;
    const floatx4* xr = reinterpret_cast<const floatx4*>(
        x + (long long)node_a * IN_CH + quad * 8);
    const short8* bhp = reinterpret_cast<const short8*>(&w1h[m * IN_CH + quad * 8]);
    const short8* blp = reinterpret_cast<const short8*>(&w1l[m * IN_CH + quad * 8]);

    floatx4 acc = {0.f, 0.f, 0.f, 0.f};
#pragma unroll
    for (int t = 0; t < IN_CH / 32; ++t) {
        floatx4 a0 = xr[t * 8];
        floatx4 a1 = xr[t * 8 + 1];
        short8 ah, al;
#pragma unroll
        for (int j = 0; j < 4; ++j) {
            float v0 = a0[j], v1 = a1[j];
            short h0 = bf16_rne(v0), h1 = bf16_rne(v1);
            ah[j]     = h0;
            ah[j + 4] = h1;
            al[j]     = bf16_rne(v0 - bf16_to_f32(h0));
            al[j + 4] = bf16_rne(v1 - bf16_to_f32(h1));
        }
        short8 vbh = bhp[t * 4];
        short8 vbl = blp[t * 4];
        acc = __builtin_amdgcn_mfma_f32_16x16x32_bf16(ah, vbh, acc, 0, 0, 0);
        acc = __builtin_amdgcn_mfma_f32_16x16x32_bf16(al, vbh, acc, 0, 0, 0);
        acc = __builtin_amdgcn_mfma_f32_16x16x32_bf16(ah, vbl, acc, 0, 0, 0);
    }

#pragma unroll
    for (int r = 0; r < 4; ++r) {
        int node = base + quad * 4 + r;
        if (node < N_NODES) xws[node * HID + m] = acc[r] * dinv[node];
    }
}

// One wave per node: gather CSR neighbors (4 edges x 16 channels / iter),
// shuffle-reduce, fused epilogue (dinv*(sum+self)+b1)@W2+b2.
__global__ __launch_bounds__(256) void gather_kernel(const int* __restrict__ offs,
                                                     const int* __restrict__ deg,
                                                     const int* __restrict__ csr,
                                                     const float* __restrict__ xws,
                                                     const float* __restrict__ dinv,
                                                     const float* __restrict__ b1,
                                                     const float* __restrict__ W2,
                                                     const float* __restrict__ b2,
                                                     float2* __restrict__ out) {
    int wid = (blockIdx.x * 256 + threadIdx.x) >> 6;  // node index
    if (wid >= N_NODES) return;
    int lane = threadIdx.x & 63;
    int eh = lane >> 4;   // edge slot 0..3
    int ch = lane & 15;   // channel

    int start = offs[wid];
    int d = deg[wid];

    float sum = 0.f;
    for (int k = eh; k < d; k += 4) {
        int src = csr[start + k];
        sum += xws[src * HID + ch];
    }
    // reduce over the 4 edge slots (lane bits 4,5)
    sum += __shfl_xor(sum, 16);
    sum += __shfl_xor(sum, 32);

    float hv = dinv[wid] * (sum + xws[wid * HID + ch]) + b1[ch];
    float o0 = hv * W2[2 * ch];
    float o1 = hv * W2[2 * ch + 1];
    // reduce over 16 channels (lane bits 0..3)
    o0 += __shfl_xor(o0, 1);  o1 += __shfl_xor(o1, 1);
    o0 += __shfl_xor(o0, 2);  o1 += __shfl_xor(o1, 2);
    o0 += __shfl_xor(o0, 4);  o1 += __shfl_xor(o1, 4);
    o0 += __shfl_xor(o0, 8);  o1 += __shfl_xor(o1, 8);

    if (lane == 0) {
        float2 o = {o0 + b2[0], o1 + b2[1]};
        out[wid] = o;
    }
}

extern "C" void kernel_launch(void* const* d_in, const int* in_sizes, int n_in,
                              void* d_out, int out_size, void* d_ws, size_t ws_size,
                              hipStream_t stream) {
    const float* x  = (const float*)d_in[0];
    const int*   ei = (const int*)d_in[1];
    const float* W1 = (const float*)d_in[2];
    const float* b1 = (const float*)d_in[3];
    const float* W2 = (const float*)d_in[4];
    const float* b2 = (const float*)d_in[5];

    char* ws = (char*)d_ws;
    int*   deg  = (int*)  (ws + 0);
    int*   offs = (int*)  (ws + 400000);
    int*   curs = (int*)  (ws + 800000);
    int*   bsum = (int*)  (ws + 1200000);
    float* dinv = (float*)(ws + 1204096);
    float* xws  = (float*)(ws + 1604096);
    int*   csr  = (int*)  (ws + 8004096);

    hipMemsetAsync(deg, 0, 400000, stream);

    deg_kernel<<<(N_EDGES + 255) / 256, 256, 0, stream>>>(ei + N_EDGES, deg);
    scan1_kernel<<<NBLK, 256, 0, stream>>>(deg, offs, bsum);
    scan2_kernel<<<1, 512, 0, stream>>>(bsum);
    scan3_kernel<<<NBLK, 256, 0, stream>>>(deg, offs, curs, bsum, dinv);
    xw_kernel<<<(N_NODES + 63) / 64, 256, 0, stream>>>(x, W1, dinv, xws);
    fill_kernel<<<(N_EDGES + 255) / 256, 256, 0, stream>>>(ei, curs, csr);
    gather_kernel<<<(N_NODES * 64 + 255) / 256, 256, 0, stream>>>(
        offs, deg, csr, xws, dinv, b1, W2, b2, (float2*)d_out);
}

// Round 4
// 441.055 us; speedup vs baseline: 1.8178x; 1.8178x over previous
//
#include <hip/hip_runtime.h>

// GCN layer on MI355X (gfx950) — ALL tensors fp32.
// x[100000,512], edge_index[2,3200000] i32, W1[512,16], b1[16], W2[16,2], b2[2]
//   -> out[100000,2] fp32.
//
// Key folds (epilogue is linear):
//   Wc = W1@W2 [512,2],  b' = b1@W2 + b2
//   t[j]  = dinv[j] * (x@Wc)[j]          (dinv = rsqrt(indeg+1))
//   out_i = dinv_i * ( sum_{j->i} t_j + t_i ) + b'
//
// HW model from R2/R3: random EA line-ops (device atomics / partial-line
// writebacks) cost ~50ns each (~20 G/s device-wide) -> any per-edge random
// EA traffic floors at ~160us. This version has ZERO random EA ops:
// edges are binned into 391 buckets of 256 target nodes (dense streaming
// writes), then degree-count + accumulation happen in LDS atomics with
// random reads only hitting the L2-resident 800 KB t-table.

constexpr int N_NODES = 100000;
constexpr int N_EDGES = 3200000;
constexpr int IN_CH   = 512;
constexpr int HID     = 16;
constexpr int OUT_CH  = 2;

constexpr int NBUCK = (N_NODES + 255) / 256;          // 391 buckets x 256 nodes
constexpr int BIN_BLOCKS = 320;
constexpr int EPB = N_EDGES / BIN_BLOCKS;             // 10000 edges/block (exact)

typedef __attribute__((ext_vector_type(4))) float floatx4;

// ---- workspace layout (bytes) ----
// 0        Wc      float[512*2]   (4 KB)
// 4096     bconst  float[2]
// 4608     cnt     int[NBUCK]     (memset 0)
// 6400     base    int[NBUCK+1]
// 8192     cursor  int[NBUCK]
// 16384    dinv    float[N_NODES]     (400 KB)
// 416384   t       float2[N_NODES]    (800 KB)
// 1216384  binned  int[N_EDGES]       (12.8 MB)  value = (local_tgt<<20)|src

__global__ __launch_bounds__(256) void k_wc(const float* __restrict__ W1,
                                            const float* __restrict__ b1,
                                            const float* __restrict__ W2,
                                            const float* __restrict__ b2,
                                            float* __restrict__ Wc,
                                            float* __restrict__ bconst) {
    int i = blockIdx.x * 256 + threadIdx.x;  // 0..1023
    int c = i >> 1, o = i & 1;
    float s = 0.f;
#pragma unroll
    for (int h = 0; h < HID; ++h) s += W1[c * HID + h] * W2[h * OUT_CH + o];
    Wc[i] = s;
    if (i < OUT_CH) {
        float bo = b2[i];
#pragma unroll
        for (int h = 0; h < HID; ++h) bo += b1[h] * W2[h * OUT_CH + i];
        bconst[i] = bo;
    }
}

__global__ __launch_bounds__(256) void k_count(const int* __restrict__ tgt,
                                               int* __restrict__ cnt) {
    __shared__ int hist[NBUCK];
    for (int i = threadIdx.x; i < NBUCK; i += 256) hist[i] = 0;
    __syncthreads();
    int e0 = blockIdx.x * EPB;
    for (int e = e0 + threadIdx.x; e < e0 + EPB; e += 256)
        atomicAdd(&hist[tgt[e] >> 8], 1);
    __syncthreads();
    for (int i = threadIdx.x; i < NBUCK; i += 256)
        if (hist[i]) atomicAdd(&cnt[i], hist[i]);
}

__global__ __launch_bounds__(512) void k_scan(const int* __restrict__ cnt,
                                              int* __restrict__ base,
                                              int* __restrict__ cursor) {
    __shared__ int tmp[512];
    int tid = threadIdx.x;
    int v = (tid < NBUCK) ? cnt[tid] : 0;
    tmp[tid] = v;
    __syncthreads();
#pragma unroll
    for (int off = 1; off < 512; off <<= 1) {
        int tv = (tid >= off) ? tmp[tid - off] : 0;
        __syncthreads();
        tmp[tid] += tv;
        __syncthreads();
    }
    if (tid < NBUCK) { int b = tmp[tid] - v; base[tid] = b; cursor[tid] = b; }
    if (tid == NBUCK - 1) base[NBUCK] = tmp[tid];  // = N_EDGES
}

__global__ __launch_bounds__(256) void k_bin(const int* __restrict__ ei,
                                             int* __restrict__ cursor,
                                             int* __restrict__ binned) {
    __shared__ int hist[NBUCK];
    __shared__ int lbase[NBUCK];
    __shared__ int lcur[NBUCK];
    for (int i = threadIdx.x; i < NBUCK; i += 256) { hist[i] = 0; lcur[i] = 0; }
    __syncthreads();
    int e0 = blockIdx.x * EPB;
    int e1 = e0 + EPB;
    for (int e = e0 + threadIdx.x; e < e1; e += 256)
        atomicAdd(&hist[ei[N_EDGES + e] >> 8], 1);
    __syncthreads();
    for (int i = threadIdx.x; i < NBUCK; i += 256)
        lbase[i] = hist[i] ? atomicAdd(&cursor[i], hist[i]) : 0;
    __syncthreads();
    for (int e = e0 + threadIdx.x; e < e1; e += 256) {
        int tg = ei[N_EDGES + e];
        int b = tg >> 8;
        int off = atomicAdd(&lcur[b], 1);
        binned[lbase[b] + off] = ((tg & 255) << 20) | ei[e];  // src < 2^20
    }
}

// Per bucket: count local in-degrees in LDS, emit dinv (dense write).
__global__ __launch_bounds__(256) void k_dinv(const int* __restrict__ base,
                                              const int* __restrict__ binned,
                                              float* __restrict__ dinv) {
    __shared__ int cnt[256];
    cnt[threadIdx.x] = 0;
    __syncthreads();
    int b = blockIdx.x;
    int s = base[b], e = base[b + 1];
    for (int i = s + threadIdx.x; i < e; i += 256)
        atomicAdd(&cnt[binned[i] >> 20], 1);
    __syncthreads();
    int node = (b << 8) + threadIdx.x;
    if (node < N_NODES)
        dinv[node] = rsqrtf((float)(cnt[threadIdx.x] + 1));  // +1 self loop
}

// t[n] = dinv[n] * (x[n] @ Wc).  One wave per node; lane l covers channels
// [8l,8l+8) -> wave reads the 2 KB row fully coalesced (two float4 per lane).
__global__ __launch_bounds__(256) void k_xw(const float* __restrict__ x,
                                            const float* __restrict__ Wc,
                                            const float* __restrict__ dinv,
                                            float2* __restrict__ t) {
    int node = (blockIdx.x * 256 + threadIdx.x) >> 6;  // grid exact: 25000*4
    int lane = threadIdx.x & 63;
    const floatx4* xr = reinterpret_cast<const floatx4*>(
        x + (size_t)node * IN_CH + lane * 8);
    const floatx4* wr = reinterpret_cast<const floatx4*>(Wc + lane * 16);
    floatx4 x0 = xr[0], x1 = xr[1];
    floatx4 w0 = wr[0], w1 = wr[1], w2 = wr[2], w3 = wr[3];
    // Wc row-major [c][o]: float idx 2c+o with c = 8*lane+k
    float s0 = x0[0]*w0[0] + x0[1]*w0[2] + x0[2]*w1[0] + x0[3]*w1[2]
             + x1[0]*w2[0] + x1[1]*w2[2] + x1[2]*w3[0] + x1[3]*w3[2];
    float s1 = x0[0]*w0[1] + x0[1]*w0[3] + x0[2]*w1[1] + x0[3]*w1[3]
             + x1[0]*w2[1] + x1[1]*w2[3] + x1[2]*w3[1] + x1[3]*w3[3];
    s0 += __shfl_xor(s0, 32); s1 += __shfl_xor(s1, 32);
    s0 += __shfl_xor(s0, 16); s1 += __shfl_xor(s1, 16);
    s0 += __shfl_xor(s0, 8);  s1 += __shfl_xor(s1, 8);
    s0 += __shfl_xor(s0, 4);  s1 += __shfl_xor(s1, 4);
    s0 += __shfl_xor(s0, 2);  s1 += __shfl_xor(s1, 2);
    s0 += __shfl_xor(s0, 1);  s1 += __shfl_xor(s1, 1);
    if (lane == 0) {
        float di = dinv[node];
        t[node] = make_float2(di * s0, di * s1);
    }
}

// Per bucket: accumulate t[src] into LDS, fused epilogue, dense out write.
__global__ __launch_bounds__(256) void k_acc(const int* __restrict__ base,
                                             const int* __restrict__ binned,
                                             const float2* __restrict__ t,
                                             const float* __restrict__ dinv,
                                             const float* __restrict__ bconst,
                                             float2* __restrict__ out) {
    __shared__ float acc0[256];
    __shared__ float acc1[256];
    acc0[threadIdx.x] = 0.f;
    acc1[threadIdx.x] = 0.f;
    __syncthreads();
    int b = blockIdx.x;
    int s = base[b], e = base[b + 1];
    for (int i = s + threadIdx.x; i < e; i += 256) {
        int v = binned[i];
        int local = v >> 20;
        int src = v & 0xFFFFF;
        float2 ts = t[src];             // 800 KB table: L2-resident random read
        atomicAdd(&acc0[local], ts.x);  // LDS atomics, not EA
        atomicAdd(&acc1[local], ts.y);
    }
    __syncthreads();
    int node = (b << 8) + threadIdx.x;
    if (node < N_NODES) {
        float2 self = t[node];
        float di = dinv[node];
        out[node] = make_float2(di * (acc0[threadIdx.x] + self.x) + bconst[0],
                                di * (acc1[threadIdx.x] + self.y) + bconst[1]);
    }
}

extern "C" void kernel_launch(void* const* d_in, const int* in_sizes, int n_in,
                              void* d_out, int out_size, void* d_ws, size_t ws_size,
                              hipStream_t stream) {
    const float* x  = (const float*)d_in[0];
    const int*   ei = (const int*)d_in[1];
    const float* W1 = (const float*)d_in[2];
    const float* b1 = (const float*)d_in[3];
    const float* W2 = (const float*)d_in[4];
    const float* b2 = (const float*)d_in[5];

    char* ws = (char*)d_ws;
    float*  Wc     = (float*) (ws + 0);
    float*  bconst = (float*) (ws + 4096);
    int*    cnt    = (int*)   (ws + 4608);
    int*    basep  = (int*)   (ws + 6400);
    int*    cursor = (int*)   (ws + 8192);
    float*  dinv   = (float*) (ws + 16384);
    float2* t      = (float2*)(ws + 416384);
    int*    binned = (int*)   (ws + 1216384);

    hipMemsetAsync(cnt, 0, NBUCK * sizeof(int), stream);

    k_wc   <<<4, 256, 0, stream>>>(W1, b1, W2, b2, Wc, bconst);
    k_count<<<BIN_BLOCKS, 256, 0, stream>>>(ei + N_EDGES, cnt);
    k_scan <<<1, 512, 0, stream>>>(cnt, basep, cursor);
    k_bin  <<<BIN_BLOCKS, 256, 0, stream>>>(ei, cursor, binned);
    k_dinv <<<NBUCK, 256, 0, stream>>>(basep, binned, dinv);
    k_xw   <<<(N_NODES * 64) / 256, 256, 0, stream>>>(x, Wc, dinv, t);
    k_acc  <<<NBUCK, 256, 0, stream>>>(basep, binned, t, dinv, bconst,
                                       (float2*)d_out);
}

// Round 5
// 413.361 us; speedup vs baseline: 1.9396x; 1.0670x over previous
//
#include <hip/hip_runtime.h>

// GCN layer on MI355X (gfx950) — ALL tensors fp32.
// x[100000,512], edge_index[2,3200000] i32, W1[512,16], b1[16], W2[16,2], b2[2]
//   -> out[100000,2] fp32.
//
// Folds (epilogue is linear):
//   Wc = W1@W2 [512,2],  b' = b1@W2 + b2
//   t_raw[j] = (x@Wc)[j];  after deg known: t[j] = dinv[j]*t_raw[j]
//   out_i = dinv_i * ( sum_{j->i} t_j + t_i ) + b'
//
// R5 structure (overlap-oriented):
//   K1 {per-block bucket histograms  ∪  Wc/b' fold}
//   K2a column scan of hist (per-bucket, per-block offsets)
//   K2b bucket base scan
//   K3 {bin placement (single pass, precomputed cursors)  ∪  t_raw = x@Wc}
//   K4 per-bucket degree count -> dinv; scale t in place
//   K5 per-bucket LDS accumulate + fused epilogue
// Zero random EA ops (R2/R3 showed ~50ns per random atomic/partial-line
// writeback); zero global memsets; xw's 205 MB stream hides the bin pass.

constexpr int N_NODES = 100000;
constexpr int N_EDGES = 3200000;
constexpr int IN_CH   = 512;
constexpr int HID     = 16;
constexpr int OUT_CH  = 2;

constexpr int NBUCK      = (N_NODES + 255) / 256;   // 391 buckets x 256 nodes
constexpr int BIN_BLOCKS = 320;
constexpr int EPB        = N_EDGES / BIN_BLOCKS;    // 10000 (exact)
constexpr int XW_BLOCKS  = N_NODES / 4;             // 25000 (4 nodes/block)

typedef __attribute__((ext_vector_type(4))) float floatx4;

// ---- workspace layout (bytes) ----
// 0        hist     int[320][391]  (500480)  per-block bucket counts -> offsets
// 500480   coltot   int[391]
// 502048   bbase    int[392]
// 503616   Wc       float[1024]
// 507712   bconst   float[2] (pad 16)
// 507728   dinv     float[N_NODES]   (400000)
// 907728   t2       float2[N_NODES]  (800000)
// 1707728  binned   int[N_EDGES]     (12.8 MB)  value = (local_tgt<<20)|src

__global__ __launch_bounds__(256) void k_count_wc(const int* __restrict__ tgt,
                                                  int* __restrict__ hist,
                                                  const float* __restrict__ W1,
                                                  const float* __restrict__ b1,
                                                  const float* __restrict__ W2,
                                                  const float* __restrict__ b2,
                                                  float* __restrict__ Wc,
                                                  float* __restrict__ bconst) {
    if (blockIdx.x == BIN_BLOCKS) {  // weight-fold block
        for (int i = threadIdx.x; i < IN_CH * OUT_CH; i += 256) {
            int c = i >> 1, o = i & 1;
            float s = 0.f;
#pragma unroll
            for (int h = 0; h < HID; ++h) s += W1[c * HID + h] * W2[h * OUT_CH + o];
            Wc[i] = s;
        }
        if (threadIdx.x < OUT_CH) {
            float bo = b2[threadIdx.x];
#pragma unroll
            for (int h = 0; h < HID; ++h) bo += b1[h] * W2[h * OUT_CH + threadIdx.x];
            bconst[threadIdx.x] = bo;
        }
        return;
    }
    __shared__ int h[NBUCK];
    for (int i = threadIdx.x; i < NBUCK; i += 256) h[i] = 0;
    __syncthreads();
    int e0 = blockIdx.x * EPB;
    for (int e = e0 + threadIdx.x; e < e0 + EPB; e += 256)
        atomicAdd(&h[tgt[e] >> 8], 1);
    __syncthreads();
    for (int i = threadIdx.x; i < NBUCK; i += 256)
        hist[blockIdx.x * NBUCK + i] = h[i];  // dense row, single-writer line
}

// Per bucket b: exclusive scan down the 320-block column; in-place offsets.
__global__ __launch_bounds__(64) void k_colscan(int* __restrict__ hist,
                                                int* __restrict__ coltot) {
    int b = blockIdx.x;
    int lane = threadIdx.x;          // covers blocks 5*lane .. 5*lane+4
    int v[5];
    int s = 0;
#pragma unroll
    for (int j = 0; j < 5; ++j) {
        v[j] = hist[(lane * 5 + j) * NBUCK + b];
        s += v[j];
    }
    int inc = s;
#pragma unroll
    for (int off = 1; off < 64; off <<= 1) {
        int n = __shfl_up(inc, off);
        if (lane >= off) inc += n;
    }
    int excl = inc - s;
#pragma unroll
    for (int j = 0; j < 5; ++j) {
        hist[(lane * 5 + j) * NBUCK + b] = excl;
        excl += v[j];
    }
    if (lane == 63) coltot[b] = inc;
}

__global__ __launch_bounds__(512) void k_basescan(const int* __restrict__ coltot,
                                                  int* __restrict__ bbase) {
    __shared__ int tmp[512];
    int tid = threadIdx.x;
    int v = (tid < NBUCK) ? coltot[tid] : 0;
    tmp[tid] = v;
    __syncthreads();
#pragma unroll
    for (int off = 1; off < 512; off <<= 1) {
        int tv = (tid >= off) ? tmp[tid - off] : 0;
        __syncthreads();
        tmp[tid] += tv;
        __syncthreads();
    }
    if (tid < NBUCK) bbase[tid] = tmp[tid] - v;
    if (tid == NBUCK - 1) bbase[NBUCK] = tmp[tid];  // = N_EDGES
}

// Blocks [0,320): single-pass bin placement with precomputed cursors.
// Blocks [320,25320): t_raw[n] = x[n] @ Wc (one wave per node, coalesced).
__global__ __launch_bounds__(256) void k_bin_xw(const int* __restrict__ ei,
                                                int* __restrict__ hist,
                                                const int* __restrict__ bbase,
                                                int* __restrict__ binned,
                                                const float* __restrict__ x,
                                                const float* __restrict__ Wc,
                                                float2* __restrict__ t2) {
    if (blockIdx.x < BIN_BLOCKS) {
        __shared__ int lcur[NBUCK];
        int blk = blockIdx.x;
        for (int i = threadIdx.x; i < NBUCK; i += 256)
            lcur[i] = bbase[i] + hist[blk * NBUCK + i];
        __syncthreads();
        int e0 = blk * EPB;
        for (int e = e0 + threadIdx.x; e < e0 + EPB; e += 256) {
            int tg = ei[N_EDGES + e];
            int b = tg >> 8;
            int pos = atomicAdd(&lcur[b], 1);
            binned[pos] = ((tg & 255) << 20) | ei[e];  // src < 2^20
        }
        return;
    }
    int nb = blockIdx.x - BIN_BLOCKS;
    int node = nb * 4 + (threadIdx.x >> 6);
    int lane = threadIdx.x & 63;
    const floatx4* xr = reinterpret_cast<const floatx4*>(
        x + (size_t)node * IN_CH + lane * 8);
    const floatx4* wr = reinterpret_cast<const floatx4*>(Wc + lane * 16);
    floatx4 x0 = xr[0], x1 = xr[1];
    floatx4 w0 = wr[0], w1 = wr[1], w2 = wr[2], w3 = wr[3];
    float s0 = x0[0]*w0[0] + x0[1]*w0[2] + x0[2]*w1[0] + x0[3]*w1[2]
             + x1[0]*w2[0] + x1[1]*w2[2] + x1[2]*w3[0] + x1[3]*w3[2];
    float s1 = x0[0]*w0[1] + x0[1]*w0[3] + x0[2]*w1[1] + x0[3]*w1[3]
             + x1[0]*w2[1] + x1[1]*w2[3] + x1[2]*w3[1] + x1[3]*w3[3];
    s0 += __shfl_xor(s0, 32); s1 += __shfl_xor(s1, 32);
    s0 += __shfl_xor(s0, 16); s1 += __shfl_xor(s1, 16);
    s0 += __shfl_xor(s0, 8);  s1 += __shfl_xor(s1, 8);
    s0 += __shfl_xor(s0, 4);  s1 += __shfl_xor(s1, 4);
    s0 += __shfl_xor(s0, 2);  s1 += __shfl_xor(s1, 2);
    s0 += __shfl_xor(s0, 1);  s1 += __shfl_xor(s1, 1);
    if (lane == 0) t2[node] = make_float2(s0, s1);  // RAW (no dinv yet)
}

// Per bucket: local degree count -> dinv; scale t2 in place.
__global__ __launch_bounds__(256) void k_dinv(const int* __restrict__ bbase,
                                              const int* __restrict__ binned,
                                              float* __restrict__ dinv,
                                              float2* __restrict__ t2) {
    __shared__ int cnt[256];
    cnt[threadIdx.x] = 0;
    __syncthreads();
    int b = blockIdx.x;
    int s = bbase[b], e = bbase[b + 1];
    for (int i = s + threadIdx.x; i < e; i += 256)
        atomicAdd(&cnt[binned[i] >> 20], 1);
    __syncthreads();
    int node = (b << 8) + threadIdx.x;
    if (node < N_NODES) {
        float di = rsqrtf((float)(cnt[threadIdx.x] + 1));  // +1 self loop
        dinv[node] = di;
        float2 v = t2[node];
        t2[node] = make_float2(v.x * di, v.y * di);
    }
}

// Per bucket: accumulate pre-scaled t[src] in LDS, fused epilogue, dense out.
__global__ __launch_bounds__(256) void k_acc(const int* __restrict__ bbase,
                                             const int* __restrict__ binned,
                                             const float2* __restrict__ t2,
                                             const float* __restrict__ dinv,
                                             const float* __restrict__ bconst,
                                             float2* __restrict__ out) {
    __shared__ float acc0[256];
    __shared__ float acc1[256];
    acc0[threadIdx.x] = 0.f;
    acc1[threadIdx.x] = 0.f;
    __syncthreads();
    int b = blockIdx.x;
    int s = bbase[b], e = bbase[b + 1];
    for (int i = s + threadIdx.x; i < e; i += 256) {
        int v = binned[i];
        float2 ts = t2[v & 0xFFFFF];    // L2-resident 800 KB table
        atomicAdd(&acc0[v >> 20], ts.x);
        atomicAdd(&acc1[v >> 20], ts.y);
    }
    __syncthreads();
    int node = (b << 8) + threadIdx.x;
    if (node < N_NODES) {
        float2 self = t2[node];         // already dinv-scaled
        float di = dinv[node];
        out[node] = make_float2(di * (acc0[threadIdx.x] + self.x) + bconst[0],
                                di * (acc1[threadIdx.x] + self.y) + bconst[1]);
    }
}

extern "C" void kernel_launch(void* const* d_in, const int* in_sizes, int n_in,
                              void* d_out, int out_size, void* d_ws, size_t ws_size,
                              hipStream_t stream) {
    const float* x  = (const float*)d_in[0];
    const int*   ei = (const int*)d_in[1];
    const float* W1 = (const float*)d_in[2];
    const float* b1 = (const float*)d_in[3];
    const float* W2 = (const float*)d_in[4];
    const float* b2 = (const float*)d_in[5];

    char* ws = (char*)d_ws;
    int*    hist   = (int*)   (ws + 0);
    int*    coltot = (int*)   (ws + 500480);
    int*    bbase  = (int*)   (ws + 502048);
    float*  Wc     = (float*) (ws + 503616);
    float*  bconst = (float*) (ws + 507712);
    float*  dinv   = (float*) (ws + 507728);
    float2* t2     = (float2*)(ws + 907728);
    int*    binned = (int*)   (ws + 1707728);

    k_count_wc<<<BIN_BLOCKS + 1, 256, 0, stream>>>(ei + N_EDGES, hist,
                                                   W1, b1, W2, b2, Wc, bconst);
    k_colscan <<<NBUCK, 64, 0, stream>>>(hist, coltot);
    k_basescan<<<1, 512, 0, stream>>>(coltot, bbase);
    k_bin_xw  <<<BIN_BLOCKS + XW_BLOCKS, 256, 0, stream>>>(ei, hist, bbase,
                                                           binned, x, Wc, t2);
    k_dinv    <<<NBUCK, 256, 0, stream>>>(bbase, binned, dinv, t2);
    k_acc     <<<NBUCK, 256, 0, stream>>>(bbase, binned, t2, dinv, bconst,
                                          (float2*)d_out);
}